// Round 4
// baseline (125.867 us; speedup 1.0000x reference)
//
#include <hip/hip_runtime.h>
#include <stdint.h>

#define IN_F     4096
#define OUT_F    4096
#define BATCH    128
#define NNZ      1600000
#define NSEG     250       // sort segments; block s owns entries [s*6400, +6400)
#define CHUNKSEG 6400      // NNZ / NSEG exactly
#define CNTR     4096      // cntoff stride per segment (= OUT_F)
#define DR       4         // k_dense rows per block (64 KB LDS)
#define NCH      16        // split-K chunks
#define KCH      256       // K per chunk
#define NGRAN    (IN_F / 8)  // 512 k-granules of 8 bf16

typedef float f32x4_t __attribute__((ext_vector_type(4)));
typedef short s16x8_t __attribute__((ext_vector_type(8)));

// fp32 -> bf16 bits (RNE)
__device__ __forceinline__ unsigned f2bf(float f) {
  unsigned u = __float_as_uint(f);
  return (u + 0x7fffu + ((u >> 16) & 1u)) >> 16;
}

// ---------- K0: convert inp -> granule-major bf16 B: bg[g][row], g = k/8 ----------
__global__ __launch_bounds__(256) void k_prep3(const float* __restrict__ inp,
                                               uint4* __restrict__ bg) {
  const int t = threadIdx.x;
  const int row = blockIdx.x;                       // 0..127
  const float4* __restrict__ src = (const float4*)(inp + (size_t)row * IN_F);
  #pragma unroll
  for (int j = 0; j < 2; ++j) {
    const int g = 2 * t + j;                        // 0..511
    const float4 a = src[2 * g];
    const float4 b = src[2 * g + 1];
    uint4 o;
    o.x = f2bf(a.x) | (f2bf(a.y) << 16);
    o.y = f2bf(a.z) | (f2bf(a.w) << 16);
    o.z = f2bf(b.x) | (f2bf(b.y) << 16);
    o.w = f2bf(b.z) | (f2bf(b.w) << 16);
    bg[(size_t)g * BATCH + row] = o;
  }
}

// ---------- K1: per-block LDS counting sort (round-0 verified, verbatim) ----------
__global__ __launch_bounds__(1024) void k_segscat2(const float* __restrict__ vals,
                                                   const int* __restrict__ rows,
                                                   const int* __restrict__ cols,
                                                   unsigned* __restrict__ cntoff,
                                                   unsigned* __restrict__ gentries) {
  __shared__ unsigned pos[OUT_F];
  __shared__ unsigned sebuf[CHUNKSEG];
  __shared__ unsigned wsum[16];
  const int t = threadIdx.x;
  const int s = blockIdx.x;
  const int lane = t & 63;
  const int wid  = t >> 6;

  for (int i = t; i < OUT_F; i += 1024) pos[i] = 0u;
  __syncthreads();

  const size_t vbase = (size_t)s * (CHUNKSEG / 4);
  const size_t ja = vbase + t;
  const int4   ra = ((const int4*)rows)[ja];
  const int4   ca = ((const int4*)cols)[ja];
  const float4 va = ((const float4*)vals)[ja];
  const bool hasB = (t + 1024) < (CHUNKSEG / 4);
  int4 rb = make_int4(0, 0, 0, 0), cb = rb;
  float4 vb = make_float4(0.f, 0.f, 0.f, 0.f);
  if (hasB) {
    const size_t jb = ja + 1024;
    rb = ((const int4*)rows)[jb];
    cb = ((const int4*)cols)[jb];
    vb = ((const float4*)vals)[jb];
  }

  atomicAdd(&pos[ra.x], 1u); atomicAdd(&pos[ra.y], 1u);
  atomicAdd(&pos[ra.z], 1u); atomicAdd(&pos[ra.w], 1u);
  if (hasB) {
    atomicAdd(&pos[rb.x], 1u); atomicAdd(&pos[rb.y], 1u);
    atomicAdd(&pos[rb.z], 1u); atomicAdd(&pos[rb.w], 1u);
  }
  __syncthreads();

  const unsigned c0 = pos[4 * t], c1 = pos[4 * t + 1];
  const unsigned c2 = pos[4 * t + 2], c3 = pos[4 * t + 3];
  const unsigned tsum = c0 + c1 + c2 + c3;
  unsigned incl = tsum;
  #pragma unroll
  for (int d = 1; d < 64; d <<= 1) {
    const unsigned u = __shfl_up(incl, d, 64);
    if (lane >= d) incl += u;
  }
  if (lane == 63) wsum[wid] = incl;
  __syncthreads();
  if (wid == 0) {
    const unsigned v = (lane < 16) ? wsum[lane] : 0u;
    unsigned inc2 = v;
    #pragma unroll
    for (int d = 1; d < 16; d <<= 1) {
      const unsigned u = __shfl_up(inc2, d, 64);
      if (lane >= d) inc2 += u;
    }
    if (lane < 16) wsum[lane] = inc2 - v;
  }
  __syncthreads();
  const unsigned base = wsum[wid] + (incl - tsum);
  const unsigned o0 = base, o1 = o0 + c0, o2 = o1 + c1, o3 = o2 + c2;
  ((uint4*)(cntoff + (size_t)s * CNTR))[t] =
      make_uint4((o0 << 16) | c0, (o1 << 16) | c1, (o2 << 16) | c2, (o3 << 16) | c3);
  __syncthreads();
  pos[4 * t] = o0; pos[4 * t + 1] = o1; pos[4 * t + 2] = o2; pos[4 * t + 3] = o3;
  __syncthreads();

  unsigned p;
  p = atomicAdd(&pos[ra.x], 1u); sebuf[p] = (f2bf(va.x) << 16) | (unsigned)ca.x;
  p = atomicAdd(&pos[ra.y], 1u); sebuf[p] = (f2bf(va.y) << 16) | (unsigned)ca.y;
  p = atomicAdd(&pos[ra.z], 1u); sebuf[p] = (f2bf(va.z) << 16) | (unsigned)ca.z;
  p = atomicAdd(&pos[ra.w], 1u); sebuf[p] = (f2bf(va.w) << 16) | (unsigned)ca.w;
  if (hasB) {
    p = atomicAdd(&pos[rb.x], 1u); sebuf[p] = (f2bf(vb.x) << 16) | (unsigned)cb.x;
    p = atomicAdd(&pos[rb.y], 1u); sebuf[p] = (f2bf(vb.y) << 16) | (unsigned)cb.y;
    p = atomicAdd(&pos[rb.z], 1u); sebuf[p] = (f2bf(vb.z) << 16) | (unsigned)cb.z;
    p = atomicAdd(&pos[rb.w], 1u); sebuf[p] = (f2bf(vb.w) << 16) | (unsigned)cb.w;
  }
  __syncthreads();

  uint4* __restrict__ dst = (uint4*)(gentries + (size_t)s * CHUNKSEG);
  const uint4* __restrict__ srcv = (const uint4*)sebuf;
  dst[t] = srcv[t];
  if (hasB) dst[t + 1024] = srcv[t + 1024];
}

// ---------- K2: densify -> granule-major bf16 W: wg[g][row] ----------
// Block owns rows [4*bx, +4) in 64KB LDS fp32; cntoff prefetched (4 independent
// loads) then per-bucket contiguous entry runs accumulated via LDS atomics.
__global__ __launch_bounds__(256) void k_dense(const unsigned* __restrict__ gentries,
                                               const unsigned* __restrict__ cntoff,
                                               uint4* __restrict__ wg) {
  __shared__ float lrow[DR][IN_F];                  // 64 KB
  const int t    = threadIdx.x;
  const int lane = t & 63;
  const int wid  = t >> 6;
  const int r0   = blockIdx.x * DR;

  #pragma unroll
  for (int j = 0; j < 16; ++j)
    ((float4*)lrow)[j * 256 + t] = make_float4(0.f, 0.f, 0.f, 0.f);

  const int sl = lane >> 2;                         // 0..15
  const int rl = lane & 3;                          // 0..3
  unsigned co[4];
  #pragma unroll
  for (int pass = 0; pass < 4; ++pass) {
    const int s = pass * 64 + wid * 16 + sl;        // 4 waves x 16 segs x 4 passes
    co[pass] = (s < NSEG) ? cntoff[(size_t)s * CNTR + r0 + rl] : 0u;
  }
  __syncthreads();

  #pragma unroll
  for (int pass = 0; pass < 4; ++pass) {
    const int s = pass * 64 + wid * 16 + sl;
    const unsigned cnt = co[pass] & 0xffffu;
    const unsigned off = co[pass] >> 16;
    const unsigned* __restrict__ src = gentries + (size_t)s * CHUNKSEG + off;
    for (unsigned i = 0; i < cnt; ++i) {
      const unsigned e = src[i];
      atomicAdd(&lrow[rl][e & 0xffffu], __uint_as_float(e & 0xffff0000u));
    }
  }
  __syncthreads();

  #pragma unroll
  for (int j = 0; j < 8; ++j) {
    const int idx  = j * 256 + t;                   // 0..2047 = 512 g * 4 rows
    const int rowl = idx & 3;
    const int g    = idx >> 2;
    const float* p = &lrow[rowl][g * 8];
    uint4 o;
    o.x = f2bf(p[0]) | (f2bf(p[1]) << 16);
    o.y = f2bf(p[2]) | (f2bf(p[3]) << 16);
    o.z = f2bf(p[4]) | (f2bf(p[5]) << 16);
    o.w = f2bf(p[6]) | (f2bf(p[7]) << 16);
    wg[(size_t)g * OUT_F + r0 + rowl] = o;
  }
}

// ---------- K3: dense GEMM, LDS-free — both operands granule-major ----------
// C[r][b] = sum_k W[r][k]*B[b][k]. Fragment loads are coalesced plain global
// loads: lane l15 -> consecutive rows of granule g. Same MFMA math as verified:
// A lane m=l15 (row rt+l15), k-granule g=by*32+s*4+lk; B lane n=l15 (batch row
// nf*16+l15); C/D m=lk*4+j (4 consecutive W-rows), n=l15 (batch).
__global__ __launch_bounds__(256) void k_gemm3(const uint4* __restrict__ wg,
                                               const uint4* __restrict__ bg,
                                               float* __restrict__ part) {
  const int t    = threadIdx.x;
  const int lane = t & 63;
  const int wm   = t >> 6;                          // 0..3
  const int bx   = blockIdx.x;                      // M tile of 64, 0..63
  const int by   = blockIdx.y;                      // K chunk, 0..15
  const int l15  = lane & 15;
  const int lk   = lane >> 4;                       // 0..3
  const int rt   = bx * 64 + wm * 16;

  f32x4_t acc[8];
  #pragma unroll
  for (int i = 0; i < 8; ++i) { acc[i][0] = 0.f; acc[i][1] = 0.f; acc[i][2] = 0.f; acc[i][3] = 0.f; }

  const int g0 = by * 32 + lk;
  for (int s = 0; s < 8; ++s) {
    const int g = g0 + s * 4;
    const s16x8_t av = *(const s16x8_t*)&wg[(size_t)g * OUT_F + rt + l15];
    #pragma unroll
    for (int nf = 0; nf < 8; ++nf) {
      const s16x8_t bv = *(const s16x8_t*)&bg[(size_t)g * BATCH + nf * 16 + l15];
      acc[nf] = __builtin_amdgcn_mfma_f32_16x16x32_bf16(av, bv, acc[nf], 0, 0, 0);
    }
  }

  #pragma unroll
  for (int nf = 0; nf < 8; ++nf) {
    float* dst = part + (size_t)(by * BATCH + nf * 16 + l15) * OUT_F + rt + lk * 4;
    *(f32x4_t*)dst = acc[nf];
  }
}

// ---------- K4: reduce split-K partials + bias -> out [BATCH][OUT_F] ----------
__global__ __launch_bounds__(256) void k_reduce(const float* __restrict__ part,
                                                const float* __restrict__ bias,
                                                float* __restrict__ out) {
  const int idx = blockIdx.x * 256 + threadIdx.x;   // float4 index, 0..131071
  const int b   = idx >> 10;
  const int rq  = idx & 1023;
  float4 s = ((const float4*)bias)[rq];
  #pragma unroll
  for (int c = 0; c < NCH; ++c) {
    const float4 p = ((const float4*)part)[((size_t)(c * BATCH + b) << 10) + rq];
    s.x += p.x; s.y += p.y; s.z += p.z; s.w += p.w;
  }
  ((float4*)out)[idx] = s;
}

// ---------- fallback (tiny workspace): correct but slow ----------
__global__ __launch_bounds__(256) void k_init_out(const float* __restrict__ bias,
                                                  float* __restrict__ out) {
  const int i = blockIdx.x * 256 + threadIdx.x;
  out[i] = bias[i & (OUT_F - 1)];
}
__global__ __launch_bounds__(256) void k_atomic(const float* __restrict__ vals,
                                                const int* __restrict__ rows,
                                                const int* __restrict__ cols,
                                                const float* __restrict__ inp,
                                                float* __restrict__ out) {
  const int i = blockIdx.x * 256 + threadIdx.x;
  if (i >= NNZ) return;
  const float v = vals[i];
  const int   r = rows[i];
  const int   c = cols[i];
  for (int b = 0; b < BATCH; ++b)
    atomicAdd(&out[(size_t)b * OUT_F + r], v * inp[(size_t)b * IN_F + c]);
}

extern "C" void kernel_launch(void* const* d_in, const int* in_sizes, int n_in,
                              void* d_out, int out_size, void* d_ws, size_t ws_size,
                              hipStream_t stream) {
  const float* inp      = (const float*)d_in[0];
  const float* w_values = (const float*)d_in[1];
  const int*   w_rows   = (const int*)d_in[2];
  const int*   w_cols   = (const int*)d_in[3];
  const float* bias     = (const float*)d_in[4];
  float*       out      = (float*)d_out;

  const size_t w_bytes   = (size_t)NGRAN * OUT_F * 16;      // 32 MB granule-major W
  const size_t ibf_bytes = (size_t)NGRAN * BATCH * 16;      // 1 MB granule-major B
  const size_t part_bytes= (size_t)NCH * BATCH * OUT_F * 4; // 32 MB
  const size_t co_bytes  = (size_t)NSEG * CNTR * 4;         // 4.1 MB
  const size_t ent_bytes = (size_t)NSEG * CHUNKSEG * 4;     // 6.4 MB
  const size_t need = w_bytes + ibf_bytes + part_bytes + co_bytes + ent_bytes + 64;

  if (ws_size >= need) {
    char* ws = (char*)d_ws;
    uint4*    wg       = (uint4*)ws;     ws += w_bytes;
    uint4*    bg       = (uint4*)ws;     ws += ibf_bytes;
    float*    part     = (float*)ws;     ws += part_bytes;
    unsigned* cntoff   = (unsigned*)ws;  ws += co_bytes;
    unsigned* gentries = (unsigned*)ws;

    k_prep3<<<BATCH, 256, 0, stream>>>(inp, bg);
    k_segscat2<<<NSEG, 1024, 0, stream>>>(w_values, w_rows, w_cols, cntoff, gentries);
    k_dense<<<OUT_F / DR, 256, 0, stream>>>(gentries, cntoff, wg);
    k_gemm3<<<dim3(OUT_F / 64, NCH), 256, 0, stream>>>(wg, bg, part);
    k_reduce<<<(BATCH * OUT_F / 4) / 256, 256, 0, stream>>>(part, bias, out);
  } else {
    k_init_out<<<(BATCH * OUT_F) / 256, 256, 0, stream>>>(bias, out);
    k_atomic<<<(NNZ + 255) / 256, 256, 0, stream>>>(w_values, w_rows, w_cols, inp, out);
  }
}

// Round 5
// 117.695 us; speedup vs baseline: 1.0694x; 1.0694x over previous
//
#include <hip/hip_runtime.h>
#include <stdint.h>

#define IN_F     4096
#define OUT_F    4096
#define BATCH    128
#define NNZ      1600000
#define NSEG     250       // sort segments; block s owns entries [s*6400, +6400)
#define CHUNKSEG 6400      // NNZ / NSEG exactly
#define CNTR     4096      // cntoff stride per segment (= OUT_F)
#define DR       4         // k_dense rows per block (64 KB LDS)
#define NGRAN    (IN_F / 8)  // 512 k-granules of 8 bf16
#define PBLK     32        // prep blocks fused into sort launch

typedef float f32x4_t __attribute__((ext_vector_type(4)));
typedef short s16x8_t __attribute__((ext_vector_type(8)));

// fp32 -> bf16 bits (RNE)
__device__ __forceinline__ unsigned f2bf(float f) {
  unsigned u = __float_as_uint(f);
  return (u + 0x7fffu + ((u >> 16) & 1u)) >> 16;
}

// ---------- K1: fused {per-block LDS counting sort (verified)} + {B convert} -------
// Blocks [0,NSEG): sort. Blocks [NSEG, NSEG+PBLK): inp -> granule-major bf16 bg[g][row].
__global__ __launch_bounds__(1024) void k_sort_prep(const float* __restrict__ vals,
                                                    const int* __restrict__ rows,
                                                    const int* __restrict__ cols,
                                                    const float* __restrict__ inp,
                                                    unsigned* __restrict__ cntoff,
                                                    unsigned* __restrict__ gentries,
                                                    uint4* __restrict__ bg) {
  __shared__ unsigned pos[OUT_F];
  __shared__ unsigned sebuf[CHUNKSEG];
  __shared__ unsigned wsum[16];
  const int t = threadIdx.x;
  const int s = blockIdx.x;

  if (s >= NSEG) {                                  // ---- prep branch ----
    const int bp  = s - NSEG;                       // 0..31
    const int row = bp * 4 + (t >> 8);              // 0..127
    const int tt  = t & 255;
    const float4* __restrict__ src = (const float4*)(inp + (size_t)row * IN_F);
    #pragma unroll
    for (int j = 0; j < 2; ++j) {
      const int g = 2 * tt + j;                     // 0..511
      const float4 a = src[2 * g];
      const float4 b = src[2 * g + 1];
      uint4 o;
      o.x = f2bf(a.x) | (f2bf(a.y) << 16);
      o.y = f2bf(a.z) | (f2bf(a.w) << 16);
      o.z = f2bf(b.x) | (f2bf(b.y) << 16);
      o.w = f2bf(b.z) | (f2bf(b.w) << 16);
      bg[(size_t)g * BATCH + row] = o;
    }
    return;
  }

  const int lane = t & 63;
  const int wid  = t >> 6;

  for (int i = t; i < OUT_F; i += 1024) pos[i] = 0u;
  __syncthreads();

  const size_t vbase = (size_t)s * (CHUNKSEG / 4);
  const size_t ja = vbase + t;
  const int4   ra = ((const int4*)rows)[ja];
  const int4   ca = ((const int4*)cols)[ja];
  const float4 va = ((const float4*)vals)[ja];
  const bool hasB = (t + 1024) < (CHUNKSEG / 4);
  int4 rb = make_int4(0, 0, 0, 0), cb = rb;
  float4 vb = make_float4(0.f, 0.f, 0.f, 0.f);
  if (hasB) {
    const size_t jb = ja + 1024;
    rb = ((const int4*)rows)[jb];
    cb = ((const int4*)cols)[jb];
    vb = ((const float4*)vals)[jb];
  }

  atomicAdd(&pos[ra.x], 1u); atomicAdd(&pos[ra.y], 1u);
  atomicAdd(&pos[ra.z], 1u); atomicAdd(&pos[ra.w], 1u);
  if (hasB) {
    atomicAdd(&pos[rb.x], 1u); atomicAdd(&pos[rb.y], 1u);
    atomicAdd(&pos[rb.z], 1u); atomicAdd(&pos[rb.w], 1u);
  }
  __syncthreads();

  const unsigned c0 = pos[4 * t], c1 = pos[4 * t + 1];
  const unsigned c2 = pos[4 * t + 2], c3 = pos[4 * t + 3];
  const unsigned tsum = c0 + c1 + c2 + c3;
  unsigned incl = tsum;
  #pragma unroll
  for (int d = 1; d < 64; d <<= 1) {
    const unsigned u = __shfl_up(incl, d, 64);
    if (lane >= d) incl += u;
  }
  if (lane == 63) wsum[wid] = incl;
  __syncthreads();
  if (wid == 0) {
    const unsigned v = (lane < 16) ? wsum[lane] : 0u;
    unsigned inc2 = v;
    #pragma unroll
    for (int d = 1; d < 16; d <<= 1) {
      const unsigned u = __shfl_up(inc2, d, 64);
      if (lane >= d) inc2 += u;
    }
    if (lane < 16) wsum[lane] = inc2 - v;
  }
  __syncthreads();
  const unsigned base = wsum[wid] + (incl - tsum);
  const unsigned o0 = base, o1 = o0 + c0, o2 = o1 + c1, o3 = o2 + c2;
  ((uint4*)(cntoff + (size_t)s * CNTR))[t] =
      make_uint4((o0 << 16) | c0, (o1 << 16) | c1, (o2 << 16) | c2, (o3 << 16) | c3);
  __syncthreads();
  pos[4 * t] = o0; pos[4 * t + 1] = o1; pos[4 * t + 2] = o2; pos[4 * t + 3] = o3;
  __syncthreads();

  unsigned p;
  p = atomicAdd(&pos[ra.x], 1u); sebuf[p] = (f2bf(va.x) << 16) | (unsigned)ca.x;
  p = atomicAdd(&pos[ra.y], 1u); sebuf[p] = (f2bf(va.y) << 16) | (unsigned)ca.y;
  p = atomicAdd(&pos[ra.z], 1u); sebuf[p] = (f2bf(va.z) << 16) | (unsigned)ca.z;
  p = atomicAdd(&pos[ra.w], 1u); sebuf[p] = (f2bf(va.w) << 16) | (unsigned)ca.w;
  if (hasB) {
    p = atomicAdd(&pos[rb.x], 1u); sebuf[p] = (f2bf(vb.x) << 16) | (unsigned)cb.x;
    p = atomicAdd(&pos[rb.y], 1u); sebuf[p] = (f2bf(vb.y) << 16) | (unsigned)cb.y;
    p = atomicAdd(&pos[rb.z], 1u); sebuf[p] = (f2bf(vb.z) << 16) | (unsigned)cb.z;
    p = atomicAdd(&pos[rb.w], 1u); sebuf[p] = (f2bf(vb.w) << 16) | (unsigned)cb.w;
  }
  __syncthreads();

  uint4* __restrict__ dst = (uint4*)(gentries + (size_t)s * CHUNKSEG);
  const uint4* __restrict__ srcv = (const uint4*)sebuf;
  dst[t] = srcv[t];
  if (hasB) dst[t + 1024] = srcv[t + 1024];
}

// ---------- K2: densify -> granule-major bf16 W: wg[g][row] (verified r3/r4) -------
__global__ __launch_bounds__(256) void k_dense(const unsigned* __restrict__ gentries,
                                               const unsigned* __restrict__ cntoff,
                                               uint4* __restrict__ wg) {
  __shared__ float lrow[DR][IN_F];                  // 64 KB
  const int t    = threadIdx.x;
  const int lane = t & 63;
  const int wid  = t >> 6;
  const int r0   = blockIdx.x * DR;

  #pragma unroll
  for (int j = 0; j < 16; ++j)
    ((float4*)lrow)[j * 256 + t] = make_float4(0.f, 0.f, 0.f, 0.f);

  const int sl = lane >> 2;                         // 0..15
  const int rl = lane & 3;                          // 0..3
  unsigned co[4];
  #pragma unroll
  for (int pass = 0; pass < 4; ++pass) {
    const int s = pass * 64 + wid * 16 + sl;        // 4 waves x 16 segs x 4 passes
    co[pass] = (s < NSEG) ? cntoff[(size_t)s * CNTR + r0 + rl] : 0u;
  }
  __syncthreads();

  #pragma unroll
  for (int pass = 0; pass < 4; ++pass) {
    const int s = pass * 64 + wid * 16 + sl;
    const unsigned cnt = co[pass] & 0xffffu;
    const unsigned off = co[pass] >> 16;
    const unsigned* __restrict__ src = gentries + (size_t)s * CHUNKSEG + off;
    for (unsigned i = 0; i < cnt; ++i) {
      const unsigned e = src[i];
      atomicAdd(&lrow[rl][e & 0xffffu], __uint_as_float(e & 0xffff0000u));
    }
  }
  __syncthreads();

  #pragma unroll
  for (int j = 0; j < 8; ++j) {
    const int idx  = j * 256 + t;                   // 0..2047 = 512 g * 4 rows
    const int rowl = idx & 3;
    const int g    = idx >> 2;
    const float* p = &lrow[rowl][g * 8];
    uint4 o;
    o.x = f2bf(p[0]) | (f2bf(p[1]) << 16);
    o.y = f2bf(p[2]) | (f2bf(p[3]) << 16);
    o.z = f2bf(p[4]) | (f2bf(p[5]) << 16);
    o.w = f2bf(p[6]) | (f2bf(p[7]) << 16);
    wg[(size_t)g * OUT_F + r0 + rowl] = o;
  }
}

// ---------- K3: full-K GEMM, no split-K partials -> out directly ----------
// Grid 256 blocks (1/CU), 8 waves each. Wave w owns K range [w*512,(w+1)*512):
// same fragment math as verified k_gemm3 (g = w*64 + s*4 + lk; A m=l15 row rt+l15;
// B n=l15 batch nf*16+l15; C/D row = rt+lk*4+j, batch = nf*16+l15). Cross-wave
// reduce in LDS (pad 20 floats: 16B-aligned, ~2-way banks), + bias, -> out.
__global__ __launch_bounds__(512) void k_gemm4(const uint4* __restrict__ wg,
                                               const uint4* __restrict__ bg,
                                               const float* __restrict__ bias,
                                               float* __restrict__ out) {
  __shared__ float red[8][BATCH][20];               // 80 KB
  const int t    = threadIdx.x;
  const int lane = t & 63;
  const int wid  = t >> 6;                          // 0..7 = K chunk
  const int bx   = blockIdx.x;                      // 0..255
  const int l15  = lane & 15;
  const int lk   = lane >> 4;                       // 0..3
  const int rt   = bx * 16;

  f32x4_t acc[8];
  #pragma unroll
  for (int i = 0; i < 8; ++i) { acc[i][0] = 0.f; acc[i][1] = 0.f; acc[i][2] = 0.f; acc[i][3] = 0.f; }

  const int g0 = wid * 64 + lk;
  for (int s = 0; s < 16; ++s) {
    const int g = g0 + s * 4;
    const s16x8_t av = *(const s16x8_t*)&wg[(size_t)g * OUT_F + rt + l15];
    #pragma unroll
    for (int nf = 0; nf < 8; ++nf) {
      const s16x8_t bv = *(const s16x8_t*)&bg[(size_t)g * BATCH + nf * 16 + l15];
      acc[nf] = __builtin_amdgcn_mfma_f32_16x16x32_bf16(av, bv, acc[nf], 0, 0, 0);
    }
  }

  #pragma unroll
  for (int nf = 0; nf < 8; ++nf)
    *(f32x4_t*)&red[wid][nf * 16 + l15][lk * 4] = acc[nf];
  __syncthreads();

  const int b   = t >> 2;                           // 0..127
  const int rr0 = (t & 3) * 4;                      // 0,4,8,12
  float4 sum = *(const float4*)&bias[rt + rr0];
  #pragma unroll
  for (int w = 0; w < 8; ++w) {
    const float4 p = *(const float4*)&red[w][b][rr0];
    sum.x += p.x; sum.y += p.y; sum.z += p.z; sum.w += p.w;
  }
  *(float4*)&out[(size_t)b * OUT_F + rt + rr0] = sum;
}

// ---------- fallback (tiny workspace): correct but slow ----------
__global__ __launch_bounds__(256) void k_init_out(const float* __restrict__ bias,
                                                  float* __restrict__ out) {
  const int i = blockIdx.x * 256 + threadIdx.x;
  out[i] = bias[i & (OUT_F - 1)];
}
__global__ __launch_bounds__(256) void k_atomic(const float* __restrict__ vals,
                                                const int* __restrict__ rows,
                                                const int* __restrict__ cols,
                                                const float* __restrict__ inp,
                                                float* __restrict__ out) {
  const int i = blockIdx.x * 256 + threadIdx.x;
  if (i >= NNZ) return;
  const float v = vals[i];
  const int   r = rows[i];
  const int   c = cols[i];
  for (int b = 0; b < BATCH; ++b)
    atomicAdd(&out[(size_t)b * OUT_F + r], v * inp[(size_t)b * IN_F + c]);
}

extern "C" void kernel_launch(void* const* d_in, const int* in_sizes, int n_in,
                              void* d_out, int out_size, void* d_ws, size_t ws_size,
                              hipStream_t stream) {
  const float* inp      = (const float*)d_in[0];
  const float* w_values = (const float*)d_in[1];
  const int*   w_rows   = (const int*)d_in[2];
  const int*   w_cols   = (const int*)d_in[3];
  const float* bias     = (const float*)d_in[4];
  float*       out      = (float*)d_out;

  const size_t w_bytes   = (size_t)NGRAN * OUT_F * 16;      // 32 MB granule-major W
  const size_t ibf_bytes = (size_t)NGRAN * BATCH * 16;      // 1 MB granule-major B
  const size_t co_bytes  = (size_t)NSEG * CNTR * 4;         // 4.1 MB
  const size_t ent_bytes = (size_t)NSEG * CHUNKSEG * 4;     // 6.4 MB
  const size_t need = w_bytes + ibf_bytes + co_bytes + ent_bytes + 64;

  if (ws_size >= need) {
    char* ws = (char*)d_ws;
    uint4*    wg       = (uint4*)ws;     ws += w_bytes;
    uint4*    bg       = (uint4*)ws;     ws += ibf_bytes;
    unsigned* cntoff   = (unsigned*)ws;  ws += co_bytes;
    unsigned* gentries = (unsigned*)ws;

    k_sort_prep<<<NSEG + PBLK, 1024, 0, stream>>>(w_values, w_rows, w_cols, inp,
                                                  cntoff, gentries, bg);
    k_dense<<<OUT_F / DR, 256, 0, stream>>>(gentries, cntoff, wg);
    k_gemm4<<<OUT_F / 16, 512, 0, stream>>>(wg, bg, bias, out);
  } else {
    k_init_out<<<(BATCH * OUT_F) / 256, 256, 0, stream>>>(bias, out);
    k_atomic<<<(NNZ + 255) / 256, 256, 0, stream>>>(w_values, w_rows, w_cols, inp, out);
  }
}